// Round 1
// baseline (891.402 us; speedup 1.0000x reference)
//
#include <hip/hip_runtime.h>
#include <math.h>

#define NFEAT 128
#define NHID 64
#define NCLASS 40

// ---------------------------------------------------------------------------
// deg / dinv
// ---------------------------------------------------------------------------
__global__ void init_deg_kernel(int* __restrict__ deg, int n) {
    int i = blockIdx.x * blockDim.x + threadIdx.x;
    if (i < n) deg[i] = 1;  // self-loop counts once
}

__global__ void count_deg_kernel(const int* __restrict__ src, int E,
                                 int* __restrict__ deg) {
    int i = blockIdx.x * blockDim.x + threadIdx.x;
    int stride = gridDim.x * blockDim.x;
    for (int e = i; e < E; e += stride) atomicAdd(&deg[src[e]], 1);
}

__global__ void dinv_kernel(float* __restrict__ dinv_io, int n) {
    int i = blockIdx.x * blockDim.x + threadIdx.x;
    if (i < n) {
        int d = ((const int*)dinv_io)[i];
        dinv_io[i] = rsqrtf((float)d);
    }
}

// ---------------------------------------------------------------------------
// H1 = x @ W1 + b1    (M=100000, K=128, N=64)  one wave per node
// ---------------------------------------------------------------------------
__global__ __launch_bounds__(256) void gemm1_kernel(
    const float* __restrict__ x, const float* __restrict__ W1,
    const float* __restrict__ b1, float* __restrict__ H1, int n) {
    __shared__ float Wl[NFEAT * NHID];   // 32 KB
    __shared__ float xr[4][NFEAT];       // 2 KB
    for (int t = threadIdx.x; t < NFEAT * NHID; t += 256) Wl[t] = W1[t];
    __syncthreads();
    int wave = threadIdx.x >> 6;
    int lane = threadIdx.x & 63;
    float bias = b1[lane];
    int stride = gridDim.x * 4;
    for (int node = blockIdx.x * 4 + wave; node < n; node += stride) {
        xr[wave][lane]      = x[node * NFEAT + lane];
        xr[wave][lane + 64] = x[node * NFEAT + 64 + lane];
        float acc = bias;
#pragma unroll
        for (int k = 0; k < NFEAT; ++k)
            acc += xr[wave][k] * Wl[k * NHID + lane];
        H1[node * NHID + lane] = acc;
    }
}

// ---------------------------------------------------------------------------
// SpMM1: AGG1[dst][f] += dinv[src]*dinv[dst]*H1[src][f]   (f in [0,64))
// one thread per (edge, feature); 64 consecutive threads share an edge
// ---------------------------------------------------------------------------
__global__ void spmm1_kernel(const int* __restrict__ src,
                             const int* __restrict__ dst,
                             const float* __restrict__ dinv,
                             const float* __restrict__ H1,
                             float* __restrict__ AGG1, int total) {
    int i = blockIdx.x * blockDim.x + threadIdx.x;
    int stride = gridDim.x * blockDim.x;
    for (; i < total; i += stride) {
        int e = i >> 6;
        int f = i & 63;
        int s = src[e], d = dst[e];
        float nm = dinv[s] * dinv[d];
        atomicAdd(&AGG1[d * NHID + f], nm * H1[s * NHID + f]);
    }
}

// ---------------------------------------------------------------------------
// H2[n][c] = b2[c] + sum_h relu(AGG1[n][h] + dinv[n]^2*H1[n][h]) * W2[h][c]
// one wave per node; lanes 0..39 produce outputs
// ---------------------------------------------------------------------------
__global__ __launch_bounds__(256) void gemm2_kernel(
    const float* __restrict__ AGG1, const float* __restrict__ H1,
    const float* __restrict__ dinv, const float* __restrict__ W2,
    const float* __restrict__ b2, float* __restrict__ H2, int n) {
    __shared__ float W2l[NHID * NCLASS];  // 10 KB
    __shared__ float rl[4][NHID];
    for (int t = threadIdx.x; t < NHID * NCLASS; t += 256) W2l[t] = W2[t];
    __syncthreads();
    int wave = threadIdx.x >> 6;
    int lane = threadIdx.x & 63;
    int stride = gridDim.x * 4;
    for (int node = blockIdx.x * 4 + wave; node < n; node += stride) {
        float di = dinv[node];
        float sl = di * di;
        float v = AGG1[node * NHID + lane] + sl * H1[node * NHID + lane];
        rl[wave][lane] = fmaxf(v, 0.f);
        if (lane < NCLASS) {
            float acc = b2[lane];
#pragma unroll
            for (int h = 0; h < NHID; ++h)
                acc += rl[wave][h] * W2l[h * NCLASS + lane];
            H2[node * NCLASS + lane] = acc;
        }
    }
}

// ---------------------------------------------------------------------------
// SpMM2: out[dst][c] += dinv[src]*dinv[dst]*H2[src][c]   (c in [0,40))
// one thread per (edge, class)
// ---------------------------------------------------------------------------
__global__ void spmm2_kernel(const int* __restrict__ src,
                             const int* __restrict__ dst,
                             const float* __restrict__ dinv,
                             const float* __restrict__ H2,
                             float* __restrict__ out, int total) {
    int i = blockIdx.x * blockDim.x + threadIdx.x;
    int stride = gridDim.x * blockDim.x;
    for (; i < total; i += stride) {
        int e = i / NCLASS;
        int c = i - e * NCLASS;
        int s = src[e], d = dst[e];
        float nm = dinv[s] * dinv[d];
        atomicAdd(&out[d * NCLASS + c], nm * H2[s * NCLASS + c]);
    }
}

// ---------------------------------------------------------------------------
// out[n][c] = log_softmax( out[n][c] + dinv[n]^2 * H2[n][c] )
// one wave per node; lanes >= NCLASS idle through reductions
// ---------------------------------------------------------------------------
__global__ __launch_bounds__(256) void lsm_kernel(float* __restrict__ out,
                                                  const float* __restrict__ H2,
                                                  const float* __restrict__ dinv,
                                                  int n) {
    int wave = threadIdx.x >> 6;
    int lane = threadIdx.x & 63;
    int stride = gridDim.x * 4;
    for (int node = blockIdx.x * 4 + wave; node < n; node += stride) {
        float di = dinv[node];
        float sl = di * di;
        float val = 0.f;
        float v = -INFINITY;
        if (lane < NCLASS) {
            val = out[node * NCLASS + lane] + sl * H2[node * NCLASS + lane];
            v = val;
        }
#pragma unroll
        for (int off = 32; off; off >>= 1) v = fmaxf(v, __shfl_xor(v, off, 64));
        float ex = (lane < NCLASS) ? expf(val - v) : 0.f;
#pragma unroll
        for (int off = 32; off; off >>= 1) ex += __shfl_xor(ex, off, 64);
        float lse = logf(ex) + v;
        if (lane < NCLASS) out[node * NCLASS + lane] = val - lse;
    }
}

// ---------------------------------------------------------------------------
extern "C" void kernel_launch(void* const* d_in, const int* in_sizes, int n_in,
                              void* d_out, int out_size, void* d_ws, size_t ws_size,
                              hipStream_t stream) {
    const float* x  = (const float*)d_in[0];
    const int*   ei = (const int*)d_in[1];
    const float* W1 = (const float*)d_in[2];
    const float* b1 = (const float*)d_in[3];
    const float* W2 = (const float*)d_in[4];
    const float* b2 = (const float*)d_in[5];
    float* out = (float*)d_out;

    const int n = in_sizes[0] / NFEAT;       // 100000
    const int E = in_sizes[1] / 2;           // 1600000
    const int* src = ei;
    const int* dst = ei + E;

    // workspace layout (bytes)
    char* ws = (char*)d_ws;
    float* dinv = (float*)ws;                                 // n floats (also deg ints)
    float* H1   = (float*)(ws + 524288);                      // n*64
    float* AGG1 = (float*)(ws + 524288 + (size_t)n * NHID * 4);
    float* H2   = (float*)(ws + 524288 + (size_t)2 * n * NHID * 4);

    // zero accumulators (d_ws/d_out are poisoned before every call)
    hipMemsetAsync(AGG1, 0, (size_t)n * NHID * 4, stream);
    hipMemsetAsync(out, 0, (size_t)n * NCLASS * 4, stream);

    int blk = 256;
    init_deg_kernel<<<(n + blk - 1) / blk, blk, 0, stream>>>((int*)dinv, n);
    count_deg_kernel<<<2048, blk, 0, stream>>>(src, E, (int*)dinv);
    dinv_kernel<<<(n + blk - 1) / blk, blk, 0, stream>>>(dinv, n);

    gemm1_kernel<<<2048, blk, 0, stream>>>(x, W1, b1, H1, n);

    int total1 = E * NHID;  // 102.4M
    spmm1_kernel<<<8192, blk, 0, stream>>>(src, dst, dinv, H1, AGG1, total1);

    gemm2_kernel<<<2048, blk, 0, stream>>>(AGG1, H1, dinv, W2, b2, H2, n);

    int total2 = E * NCLASS;  // 64M
    spmm2_kernel<<<8192, blk, 0, stream>>>(src, dst, dinv, H2, out, total2);

    lsm_kernel<<<4096, blk, 0, stream>>>(out, H2, dinv, n);
}

// Round 2
// 592.395 us; speedup vs baseline: 1.5047x; 1.5047x over previous
//
#include <hip/hip_runtime.h>
#include <math.h>

#define NFEAT 128
#define NHID 64
#define NCLASS 40

// ---------------------------------------------------------------------------
// deg (src, +1 self-loop) and hist (dst) in one edge pass
// ---------------------------------------------------------------------------
__global__ void init_deg_kernel(int* __restrict__ deg, int n) {
    int i = blockIdx.x * blockDim.x + threadIdx.x;
    if (i < n) deg[i] = 1;  // self-loop
}

__global__ void hist_kernel(const int* __restrict__ src,
                            const int* __restrict__ dst, int E,
                            int* __restrict__ deg, int* __restrict__ hist) {
    int i = blockIdx.x * blockDim.x + threadIdx.x;
    int stride = gridDim.x * blockDim.x;
    for (int e = i; e < E; e += stride) {
        atomicAdd(&deg[src[e]], 1);
        atomicAdd(&hist[dst[e]], 1);
    }
}

__global__ void dinv_kernel(float* __restrict__ dinv_io, int n) {
    int i = blockIdx.x * blockDim.x + threadIdx.x;
    if (i < n) {
        int d = ((const int*)dinv_io)[i];
        dinv_io[i] = rsqrtf((float)d);
    }
}

// ---------------------------------------------------------------------------
// exclusive scan of hist[n] -> row_start[n+1], cursor[n]  (3 kernels)
// ---------------------------------------------------------------------------
__global__ void scan_block_kernel(const int* __restrict__ hist,
                                  int* __restrict__ scanned,
                                  int* __restrict__ bsums, int n) {
    __shared__ int tmp[256];
    int i = blockIdx.x * 256 + threadIdx.x;
    int v = (i < n) ? hist[i] : 0;
    tmp[threadIdx.x] = v;
    __syncthreads();
#pragma unroll
    for (int off = 1; off < 256; off <<= 1) {
        int t = (threadIdx.x >= off) ? tmp[threadIdx.x - off] : 0;
        __syncthreads();
        tmp[threadIdx.x] += t;
        __syncthreads();
    }
    if (i < n) scanned[i] = tmp[threadIdx.x] - v;  // exclusive
    if (threadIdx.x == 255) bsums[blockIdx.x] = tmp[255];
}

__global__ void scan_partials_kernel(int* __restrict__ bsums, int nb) {
    __shared__ int tmp[512];
    int v = (threadIdx.x < nb) ? bsums[threadIdx.x] : 0;
    tmp[threadIdx.x] = v;
    __syncthreads();
#pragma unroll
    for (int off = 1; off < 512; off <<= 1) {
        int t = (threadIdx.x >= off) ? tmp[threadIdx.x - off] : 0;
        __syncthreads();
        tmp[threadIdx.x] += t;
        __syncthreads();
    }
    if (threadIdx.x < nb) bsums[threadIdx.x] = tmp[threadIdx.x] - v;  // exclusive
}

__global__ void scan_add_kernel(const int* __restrict__ scanned,
                                const int* __restrict__ bsums,
                                int* __restrict__ row_start,
                                int* __restrict__ cursor, int n, int E) {
    int i = blockIdx.x * 256 + threadIdx.x;
    if (i < n) {
        int r = scanned[i] + bsums[blockIdx.x];
        row_start[i] = r;
        cursor[i] = r;
    }
    if (i == 0) row_start[n] = E;
}

// ---------------------------------------------------------------------------
// scatter: counting-sort edges by dst, pack {src, norm} as int2
// ---------------------------------------------------------------------------
__global__ void scatter_kernel(const int* __restrict__ src,
                               const int* __restrict__ dst,
                               const float* __restrict__ dinv,
                               int* __restrict__ cursor,
                               int2* __restrict__ es, int E) {
    int i = blockIdx.x * blockDim.x + threadIdx.x;
    int stride = gridDim.x * blockDim.x;
    for (int e = i; e < E; e += stride) {
        int s = src[e], d = dst[e];
        int pos = atomicAdd(&cursor[d], 1);
        es[pos] = make_int2(s, __float_as_int(dinv[s] * dinv[d]));
    }
}

// ---------------------------------------------------------------------------
// H1 = x @ W1 + b1    (M=100000, K=128, N=64)  one wave per node
// ---------------------------------------------------------------------------
__global__ __launch_bounds__(256) void gemm1_kernel(
    const float* __restrict__ x, const float* __restrict__ W1,
    const float* __restrict__ b1, float* __restrict__ H1, int n) {
    __shared__ float Wl[NFEAT * NHID];   // 32 KB
    __shared__ float xr[4][NFEAT];       // 2 KB
    for (int t = threadIdx.x; t < NFEAT * NHID; t += 256) Wl[t] = W1[t];
    __syncthreads();
    int wave = threadIdx.x >> 6;
    int lane = threadIdx.x & 63;
    float bias = b1[lane];
    int stride = gridDim.x * 4;
    for (int node = blockIdx.x * 4 + wave; node < n; node += stride) {
        xr[wave][lane]      = x[(size_t)node * NFEAT + lane];
        xr[wave][lane + 64] = x[(size_t)node * NFEAT + 64 + lane];
        float acc = bias;
#pragma unroll
        for (int k = 0; k < NFEAT; ++k)
            acc += xr[wave][k] * Wl[k * NHID + lane];
        H1[(size_t)node * NHID + lane] = acc;
    }
}

// ---------------------------------------------------------------------------
// fused layer-1 aggregation (gather over CSR) + self-loop + ReLU + GEMM2
// one wave per node; lane = hidden feature
// ---------------------------------------------------------------------------
__global__ __launch_bounds__(256) void agg1_gemm2_kernel(
    const int2* __restrict__ es, const int* __restrict__ row_start,
    const float* __restrict__ dinv, const float* __restrict__ H1,
    const float* __restrict__ W2, const float* __restrict__ b2,
    float* __restrict__ H2, int n) {
    __shared__ float W2l[NHID * NCLASS];  // 10 KB
    __shared__ float rl[4][NHID];
    for (int t = threadIdx.x; t < NHID * NCLASS; t += 256) W2l[t] = W2[t];
    __syncthreads();
    int wave = threadIdx.x >> 6;
    int lane = threadIdx.x & 63;
    int stride = gridDim.x * 4;
    for (int node = blockIdx.x * 4 + wave; node < n; node += stride) {
        int e0 = row_start[node], e1 = row_start[node + 1];
        float acc = 0.f;
        int e = e0;
        for (; e + 1 < e1; e += 2) {  // unroll-2: two gathers in flight
            int2 p0 = es[e];
            int2 p1 = es[e + 1];
            float v0 = H1[(size_t)p0.x * NHID + lane];
            float v1 = H1[(size_t)p1.x * NHID + lane];
            acc += __int_as_float(p0.y) * v0 + __int_as_float(p1.y) * v1;
        }
        if (e < e1) {
            int2 p = es[e];
            acc += __int_as_float(p.y) * H1[(size_t)p.x * NHID + lane];
        }
        float di = dinv[node];
        acc += di * di * H1[(size_t)node * NHID + lane];  // self-loop
        rl[wave][lane] = fmaxf(acc, 0.f);                 // wave-local, no barrier
        if (lane < NCLASS) {
            float a2 = b2[lane];
#pragma unroll
            for (int h = 0; h < NHID; ++h)
                a2 += rl[wave][h] * W2l[h * NCLASS + lane];
            H2[(size_t)node * NCLASS + lane] = a2;
        }
    }
}

// ---------------------------------------------------------------------------
// fused layer-2 aggregation + self-loop + log_softmax -> out
// one wave per node; lanes 0..39 = classes
// ---------------------------------------------------------------------------
__global__ __launch_bounds__(256) void agg2_lsm_kernel(
    const int2* __restrict__ es, const int* __restrict__ row_start,
    const float* __restrict__ dinv, const float* __restrict__ H2,
    float* __restrict__ out, int n) {
    int wave = threadIdx.x >> 6;
    int lane = threadIdx.x & 63;
    bool act = lane < NCLASS;
    int stride = gridDim.x * 4;
    for (int node = blockIdx.x * 4 + wave; node < n; node += stride) {
        int e0 = row_start[node], e1 = row_start[node + 1];
        float acc = 0.f;
        int e = e0;
        for (; e + 1 < e1; e += 2) {
            int2 p0 = es[e];
            int2 p1 = es[e + 1];
            if (act) {
                acc += __int_as_float(p0.y) * H2[(size_t)p0.x * NCLASS + lane]
                     + __int_as_float(p1.y) * H2[(size_t)p1.x * NCLASS + lane];
            }
        }
        if (e < e1) {
            int2 p = es[e];
            if (act) acc += __int_as_float(p.y) * H2[(size_t)p.x * NCLASS + lane];
        }
        float di = dinv[node];
        float val = 0.f, v = -INFINITY;
        if (act) {
            val = acc + di * di * H2[(size_t)node * NCLASS + lane];
            v = val;
        }
#pragma unroll
        for (int off = 32; off; off >>= 1) v = fmaxf(v, __shfl_xor(v, off, 64));
        float ex = act ? expf(val - v) : 0.f;
#pragma unroll
        for (int off = 32; off; off >>= 1) ex += __shfl_xor(ex, off, 64);
        float lse = logf(ex) + v;
        if (act) out[(size_t)node * NCLASS + lane] = val - lse;
    }
}

// ---------------------------------------------------------------------------
extern "C" void kernel_launch(void* const* d_in, const int* in_sizes, int n_in,
                              void* d_out, int out_size, void* d_ws, size_t ws_size,
                              hipStream_t stream) {
    const float* x  = (const float*)d_in[0];
    const int*   ei = (const int*)d_in[1];
    const float* W1 = (const float*)d_in[2];
    const float* b1 = (const float*)d_in[3];
    const float* W2 = (const float*)d_in[4];
    const float* b2 = (const float*)d_in[5];
    float* out = (float*)d_out;

    const int n = in_sizes[0] / NFEAT;       // 100000
    const int E = in_sizes[1] / 2;           // 1600000
    const int* src = ei;
    const int* dst = ei + E;

    // workspace layout (bytes), 512 KB-aligned slots for the small arrays
    char* ws = (char*)d_ws;
    float* dinv     = (float*)(ws + 0);             // n (deg ints, then dinv floats)
    int*   hist     = (int*)(ws + (512 << 10));     // n
    int*   scanned  = (int*)(ws + (1024 << 10));    // n
    int*   row_start= (int*)(ws + (1536 << 10));    // n+1
    int*   cursor   = (int*)(ws + (2048 << 10));    // n
    int*   bsums    = (int*)(ws + (2560 << 10));    // <=512
    int2*  es       = (int2*)(ws + (3 << 20));      // E int2 = 12.8 MB
    float* H1       = (float*)(ws + (16u << 20));   // n*64 = 25.6 MB
    float* H2       = (float*)(ws + (42u << 20));   // n*40 = 16 MB

    const int blk = 256;
    const int nblk_n = (n + blk - 1) / blk;  // 391

    hipMemsetAsync(hist, 0, (size_t)n * 4, stream);
    init_deg_kernel<<<nblk_n, blk, 0, stream>>>((int*)dinv, n);
    hist_kernel<<<2048, blk, 0, stream>>>(src, dst, E, (int*)dinv, hist);
    dinv_kernel<<<nblk_n, blk, 0, stream>>>(dinv, n);

    scan_block_kernel<<<nblk_n, blk, 0, stream>>>(hist, scanned, bsums, n);
    scan_partials_kernel<<<1, 512, 0, stream>>>(bsums, nblk_n);
    scan_add_kernel<<<nblk_n, blk, 0, stream>>>(scanned, bsums, row_start, cursor, n, E);

    scatter_kernel<<<2048, blk, 0, stream>>>(src, dst, dinv, cursor, es, E);

    gemm1_kernel<<<2048, blk, 0, stream>>>(x, W1, b1, H1, n);

    agg1_gemm2_kernel<<<4096, blk, 0, stream>>>(es, row_start, dinv, H1, W2, b2, H2, n);

    agg2_lsm_kernel<<<4096, blk, 0, stream>>>(es, row_start, dinv, H2, out, n);
}